// Round 6
// baseline (433.514 us; speedup 1.0000x reference)
//
#include <hip/hip_runtime.h>
#include <hip/hip_bf16.h>

// GAT layer, algebraically collapsed (same math as rounds 2-5, absmax 0.0):
//   u[b,n] = h . (W a1), v[b,n] = h . (W a2)
//   d_i = e^{u_i}*Sum_{v_j>-u_i} e^{v_j} + e^{.2u_i}*Sum_{<=} e^{.2v_j}
//   c_j = e^{v_j}*Sum_{u_i>-v_j} e^{u_i}/d_i + e^{.2v_j}*Sum_{<=} e^{.2u_i}/d_i
//   out[b,:] = (1/N) * (Sum_j c_j h[b,j,:]) @ W
// This round: ONE persistent kernel with device-scope grid barriers (was 5
// kernels; ~3us dispatch overhead each in graph replay). 512 blocks x 256 thr,
// __launch_bounds__(256,2) -> >=2 blocks/CU capacity, 512 co-resident with 4x
// wave margin. Pass phases upgraded to IR=4 (JS=32): ds_read issue 3.8->1.9us.

#define B 8
#define N 2048
#define BN (B * N)
#define FIN 128
#define FOUT 64
#define ALPHA 0.2f
#define NB 512          // grid blocks; co-resident by construction
#define JS 32           // j-slices (pass1) / i-slices (pass2)
#define SJ (N / JS)     // 64 staged elements per block

// Device-scope sense barrier. Monotonic phase avoids ABA. Counter reset by
// last arriver; reset is release-ordered before the sense store.
__device__ __forceinline__ void gbar(int* cnt, int* sense, int phase) {
    __threadfence();               // each thread makes its writes device-visible
    __syncthreads();
    if (threadIdx.x == 0) {
        if (__hip_atomic_fetch_add(cnt, 1, __ATOMIC_ACQ_REL, __HIP_MEMORY_SCOPE_AGENT) == NB - 1) {
            __hip_atomic_store(cnt, 0, __ATOMIC_RELAXED, __HIP_MEMORY_SCOPE_AGENT);
            __hip_atomic_store(sense, phase, __ATOMIC_RELEASE, __HIP_MEMORY_SCOPE_AGENT);
        } else {
            while (__hip_atomic_load(sense, __ATOMIC_ACQUIRE, __HIP_MEMORY_SCOPE_AGENT) < phase) {
                __builtin_amdgcn_s_sleep(2);
            }
        }
    }
    __syncthreads();
    __threadfence();               // each thread invalidates before reading
}

__global__ __launch_bounds__(256, 2) void gat_fused(
        const float* __restrict__ h, const float* __restrict__ W,
        const float* __restrict__ a, float* __restrict__ u, float* __restrict__ v,
        float* __restrict__ Ap, float* __restrict__ Bp, float* __restrict__ cp,
        float* __restrict__ gp, float* __restrict__ out,
        int* __restrict__ bcnt, int* __restrict__ bsense) {
    __shared__ float smem[768];
    const int t = threadIdx.x;
    const int bid = blockIdx.x;

    // ---------------- Phase A: u,v for 32 nodes/block ----------------
    {
        float* sa = smem;          // 128
        float* sw = smem + 128;    // 256
        if (t < 2 * FOUT) sa[t] = a[t];
        __syncthreads();
        {
            int kk = t >> 4, f0 = (t & 15) * 4;
            float a1x = sa[f0], a1y = sa[f0 + 1], a1z = sa[f0 + 2], a1w = sa[f0 + 3];
            float a2x = sa[FOUT + f0], a2y = sa[FOUT + f0 + 1], a2z = sa[FOUT + f0 + 2], a2w = sa[FOUT + f0 + 3];
            #pragma unroll
            for (int p = 0; p < 8; ++p) {
                int k = p * 16 + kk;
                float4 w4 = *(const float4*)(W + k * FOUT + f0);
                float p1 = w4.x * a1x + w4.y * a1y + w4.z * a1z + w4.w * a1w;
                float p2 = w4.x * a2x + w4.y * a2y + w4.z * a2z + w4.w * a2w;
                #pragma unroll
                for (int o = 1; o < 16; o <<= 1) {
                    p1 += __shfl_xor(p1, o);
                    p2 += __shfl_xor(p2, o);
                }
                if ((t & 15) == 0) { sw[k] = p1; sw[FIN + k] = p2; }
            }
        }
        __syncthreads();
        int wave = t >> 6, lane = t & 63;
        const float2 w1x = *(const float2*)(sw + lane * 2);
        const float2 w2x = *(const float2*)(sw + FIN + lane * 2);
        int node0 = bid * 32 + wave * 8;
        #pragma unroll
        for (int it = 0; it < 8; ++it) {
            int node = node0 + it;
            const float2 hx = *(const float2*)(h + (size_t)node * FIN + lane * 2);
            float p1 = hx.x * w1x.x + hx.y * w1x.y;
            float p2 = hx.x * w2x.x + hx.y * w2x.y;
            #pragma unroll
            for (int o = 32; o; o >>= 1) {
                p1 += __shfl_xor(p1, o);
                p2 += __shfl_xor(p2, o);
            }
            if (lane == 0) { u[node] = p1; v[node] = p2; }
        }
    }
    gbar(bcnt, bsense, 1);

    // ---------------- Phase B: pass-1 partials. bid = b(8) x ic(2) x js(32) ----
    {
        float* sv = smem; float* se = smem + 64; float* sf = smem + 128;
        int b = bid >> 6, ic = (bid >> 5) & 1, js = bid & 31;
        if (t < SJ) {
            float vj = v[b * N + js * SJ + t];
            sv[t] = vj;
            se[t] = expf(vj);
            sf[t] = expf(ALPHA * vj);
        }
        __syncthreads();
        float th[4], A[4], Bm[4];
        #pragma unroll
        for (int r = 0; r < 4; ++r) {
            th[r] = -u[b * N + ic * 1024 + r * 256 + t];
            A[r] = 0.f; Bm[r] = 0.f;
        }
        for (int j = 0; j < SJ; j += 4) {
            float4 vv = *(const float4*)&sv[j];
            float4 ee = *(const float4*)&se[j];
            float4 ff = *(const float4*)&sf[j];
            #pragma unroll
            for (int r = 0; r < 4; ++r) {
                A[r] += (vv.x > th[r]) ? ee.x : 0.f;  Bm[r] += (vv.x > th[r]) ? 0.f : ff.x;
                A[r] += (vv.y > th[r]) ? ee.y : 0.f;  Bm[r] += (vv.y > th[r]) ? 0.f : ff.y;
                A[r] += (vv.z > th[r]) ? ee.z : 0.f;  Bm[r] += (vv.z > th[r]) ? 0.f : ff.z;
                A[r] += (vv.w > th[r]) ? ee.w : 0.f;  Bm[r] += (vv.w > th[r]) ? 0.f : ff.w;
            }
        }
        #pragma unroll
        for (int r = 0; r < 4; ++r) {
            int i = ic * 1024 + r * 256 + t;
            Ap[js * BN + b * N + i] = A[r];
            Bp[js * BN + b * N + i] = Bm[r];
        }
    }
    gbar(bcnt, bsense, 2);

    // ---------------- Phase C: pass-2. bid = b(8) x jc(2) x is(32) ------------
    {
        float* spA = smem;             // 4 x 64
        float* spB = smem + 256;       // 4 x 64
        float* su  = smem + 512; float* sr1 = smem + 576; float* sr2 = smem + 640;
        int b = bid >> 6, jc = (bid >> 5) & 1, is = bid & 31;
        {   // reduce 32 partials for this i-slice (4 chunks of 8 across threads)
            int lane = t & 63, ch = t >> 6;
            int ii0 = b * N + is * 64 + lane;
            float pA = 0.f, pB = 0.f;
            #pragma unroll
            for (int s2 = 0; s2 < 8; ++s2) {
                int s = ch * 8 + s2;
                pA += Ap[s * BN + ii0];
                pB += Bp[s * BN + ii0];
            }
            spA[ch * 64 + lane] = pA;
            spB[ch * 64 + lane] = pB;
        }
        __syncthreads();
        if (t < 64) {
            float As = (spA[t] + spA[64 + t]) + (spA[128 + t] + spA[192 + t]);
            float Bs = (spB[t] + spB[64 + t]) + (spB[128 + t] + spB[192 + t]);
            float ui = u[b * N + is * 64 + t];
            float eu = expf(ui);
            float fu = expf(ALPHA * ui);
            float inv = 1.0f / (eu * As + fu * Bs);
            su[t] = ui; sr1[t] = eu * inv; sr2[t] = fu * inv;
        }
        __syncthreads();
        float vj[4], th[4], Cn[4], Dn[4];
        #pragma unroll
        for (int r = 0; r < 4; ++r) {
            vj[r] = v[b * N + jc * 1024 + r * 256 + t];
            th[r] = -vj[r];
            Cn[r] = 0.f; Dn[r] = 0.f;
        }
        for (int i = 0; i < 64; i += 4) {
            float4 uu = *(const float4*)&su[i];
            float4 r1 = *(const float4*)&sr1[i];
            float4 r2 = *(const float4*)&sr2[i];
            #pragma unroll
            for (int r = 0; r < 4; ++r) {
                Cn[r] += (uu.x > th[r]) ? r1.x : 0.f;  Dn[r] += (uu.x > th[r]) ? 0.f : r2.x;
                Cn[r] += (uu.y > th[r]) ? r1.y : 0.f;  Dn[r] += (uu.y > th[r]) ? 0.f : r2.y;
                Cn[r] += (uu.z > th[r]) ? r1.z : 0.f;  Dn[r] += (uu.z > th[r]) ? 0.f : r2.z;
                Cn[r] += (uu.w > th[r]) ? r1.w : 0.f;  Dn[r] += (uu.w > th[r]) ? 0.f : r2.w;
            }
        }
        #pragma unroll
        for (int r = 0; r < 4; ++r) {
            int j = jc * 1024 + r * 256 + t;
            cp[is * BN + b * N + j] = expf(vj[r]) * Cn[r] + expf(ALPHA * vj[r]) * Dn[r];
        }
    }
    gbar(bcnt, bsense, 3);

    // ---------------- Phase D: weighted column sums. bid = b(8) x ns(64) ------
    {
        float* scp = smem;          // 8 x 32
        float* sc  = smem + 256;    // 32
        float* sg2 = smem + 288;    // 2 x 128
        int b = bid >> 6, ns = bid & 63;
        {   // reduce 32 cp partials for 32 nodes (8 chunks of 4 across threads)
            int n = t & 31, ch = t >> 5;
            int nn = b * N + ns * 32 + n;
            float c = 0.f;
            #pragma unroll
            for (int s2 = 0; s2 < 4; ++s2) c += cp[(ch * 4 + s2) * BN + nn];
            scp[ch * 32 + n] = c;
        }
        __syncthreads();
        if (t < 32) {
            float c = 0.f;
            #pragma unroll
            for (int ch = 0; ch < 8; ++ch) c += scp[ch * 32 + t];
            sc[t] = c;
        }
        __syncthreads();
        int k = t & 127, half = t >> 7;
        float a0 = 0.f, a1 = 0.f;
        int base = b * N + ns * 32 + half * 16;
        #pragma unroll
        for (int n = 0; n < 16; n += 2) {
            a0 += sc[half * 16 + n]     * h[(size_t)(base + n)     * FIN + k];
            a1 += sc[half * 16 + n + 1] * h[(size_t)(base + n + 1) * FIN + k];
        }
        sg2[half * 128 + k] = a0 + a1;
        __syncthreads();
        if (t < 128) gp[(b * 64 + ns) * FIN + t] = sg2[t] + sg2[128 + t];
    }
    gbar(bcnt, bsense, 4);

    // ---------------- Phase E: out = (1/N) g @ W. blocks 0..7 only ------------
    if (bid < 8) {
        float* sred = smem;         // 2 x 128
        float* sg   = smem + 256;   // 128
        float* so   = smem + 384;   // 4 x 64
        int b = bid;
        int k = t & 127, half = t >> 7;
        float g0 = 0.f, g1 = 0.f;
        #pragma unroll
        for (int s = 0; s < 32; s += 2) {
            g0 += gp[(b * 64 + half * 32 + s)     * FIN + k];
            g1 += gp[(b * 64 + half * 32 + s + 1) * FIN + k];
        }
        sred[half * 128 + k] = g0 + g1;
        __syncthreads();
        if (t < 128) sg[t] = sred[t] + sred[128 + t];
        __syncthreads();
        int f = t & 63, q = t >> 6;
        float acc = 0.f;
        #pragma unroll
        for (int kk2 = 0; kk2 < 32; ++kk2) {
            int kk = q * 32 + kk2;
            acc += sg[kk] * W[kk * FOUT + f];
        }
        so[q * 64 + f] = acc;
        __syncthreads();
        if (t < 64)
            out[b * FOUT + t] = ((so[t] + so[64 + t]) + (so[128 + t] + so[192 + t])) * (1.0f / (float)N);
    }
}

extern "C" void kernel_launch(void* const* d_in, const int* in_sizes, int n_in,
                              void* d_out, int out_size, void* d_ws, size_t ws_size,
                              hipStream_t stream) {
    const float* h = (const float*)d_in[0];  // [B,N,FIN]
    const float* W = (const float*)d_in[1];  // [FIN,FOUT]
    const float* a = (const float*)d_in[2];  // [2*FOUT]
    float* out = (float*)d_out;              // [B,FOUT]

    // barrier state first (64 ints, zeroed each launch), then float arrays
    int* bcnt   = (int*)d_ws;
    int* bsense = bcnt + 32;
    float* ws = (float*)d_ws + 64;
    float* u  = ws;                 // BN
    float* v  = u + BN;             // BN
    float* Ap = v + BN;             // JS*BN
    float* Bp = Ap + JS * BN;       // JS*BN
    float* cp = Bp + JS * BN;       // JS*BN
    float* gp = cp + JS * BN;       // B*64*FIN

    hipMemsetAsync(d_ws, 0, 256, stream);   // zero barrier counters (capture-legal)
    gat_fused<<<NB, 256, 0, stream>>>(h, W, a, u, v, Ap, Bp, cp, gp, out, bcnt, bsense);
}

// Round 7
// 86.805 us; speedup vs baseline: 4.9941x; 4.9941x over previous
//
#include <hip/hip_runtime.h>
#include <hip/hip_bf16.h>

// GAT layer, algebraically collapsed (validated math, absmax 0.0 in R2-R6):
//   u[b,n] = h . (W a1), v[b,n] = h . (W a2)
//   d_i = e^{u_i}*Sum_{v_j>-u_i} e^{v_j} + e^{.2u_i}*Sum_{<=} e^{.2v_j}
//   c_j = e^{v_j}*Sum_{u_i>-v_j} e^{u_i}/d_i + e^{.2v_j}*Sum_{<=} e^{.2u_i}/d_i
//   out[b,:] = (1/N) * (Sum_j c_j h[b,j,:]) @ W
// R6 lesson: device-scope grid barriers cost ~95us each on 8-XCD gfx950 -> use
// discrete dispatches (graph nodes) for global sync. This round: 4 dispatches
// (K5 folds the final g@W GEMV via atomicAdd into out; K2 zero-inits out).

#define B 8
#define N 2048
#define BN (B * N)
#define FIN 128
#define FOUT 64
#define ALPHA 0.2f
#define JS 32           // j-slices (pass1) / i-slices (pass2)
#define SJ (N / JS)     // 64 staged elements per block

// ---------------- K2: u,v per node. 512 blocks x 256 thr, 32 nodes/block.
// Projection W@a1/W@a2 recomputed per block (coalesced float4, 32KB W/block).
// Block 0 additionally zero-inits out[] for K5's atomics.
__global__ __launch_bounds__(256) void k2_uv(const float* __restrict__ h,
                                             const float* __restrict__ W,
                                             const float* __restrict__ a,
                                             float* __restrict__ u, float* __restrict__ v,
                                             float* __restrict__ out) {
    __shared__ float sa[2 * FOUT];
    __shared__ float sw[2 * FIN];
    int t = threadIdx.x, bid = blockIdx.x;
    if (bid == 0) {   // zero the 512-float output for K5's atomicAdds
        out[t] = 0.f;
        out[t + 256] = 0.f;
    }
    if (t < 2 * FOUT) sa[t] = a[t];
    __syncthreads();
    {
        int kk = t >> 4, f0 = (t & 15) * 4;
        float a1x = sa[f0], a1y = sa[f0 + 1], a1z = sa[f0 + 2], a1w = sa[f0 + 3];
        float a2x = sa[FOUT + f0], a2y = sa[FOUT + f0 + 1], a2z = sa[FOUT + f0 + 2], a2w = sa[FOUT + f0 + 3];
        #pragma unroll
        for (int p = 0; p < 8; ++p) {
            int k = p * 16 + kk;
            float4 w4 = *(const float4*)(W + k * FOUT + f0);
            float p1 = w4.x * a1x + w4.y * a1y + w4.z * a1z + w4.w * a1w;
            float p2 = w4.x * a2x + w4.y * a2y + w4.z * a2z + w4.w * a2w;
            #pragma unroll
            for (int o = 1; o < 16; o <<= 1) {
                p1 += __shfl_xor(p1, o);
                p2 += __shfl_xor(p2, o);
            }
            if ((t & 15) == 0) { sw[k] = p1; sw[FIN + k] = p2; }
        }
    }
    __syncthreads();
    int wave = t >> 6, lane = t & 63;
    const float2 w1x = *(const float2*)(sw + lane * 2);
    const float2 w2x = *(const float2*)(sw + FIN + lane * 2);
    int node0 = bid * 32 + wave * 8;
    #pragma unroll
    for (int it = 0; it < 8; ++it) {
        int node = node0 + it;
        const float2 hx = *(const float2*)(h + (size_t)node * FIN + lane * 2);
        float p1 = hx.x * w1x.x + hx.y * w1x.y;
        float p2 = hx.x * w2x.x + hx.y * w2x.y;
        #pragma unroll
        for (int o = 32; o; o >>= 1) {
            p1 += __shfl_xor(p1, o);
            p2 += __shfl_xor(p2, o);
        }
        if (lane == 0) { u[node] = p1; v[node] = p2; }
    }
}

// ---------------- K3: pass-1 partials. 512 blocks = b(8) x ic(2) x js(32).
// IR=4 rows/thread; SJ=64 j's staged in LDS (wave-uniform broadcast reads).
__global__ __launch_bounds__(256) void k3_pass1(const float* __restrict__ u,
                                                const float* __restrict__ v,
                                                float* __restrict__ Ap, float* __restrict__ Bp) {
    __shared__ float sv[SJ], se[SJ], sf[SJ];
    int bid = blockIdx.x;
    int b = bid >> 6, ic = (bid >> 5) & 1, js = bid & 31;
    int t = threadIdx.x;
    if (t < SJ) {
        float vj = v[b * N + js * SJ + t];
        sv[t] = vj;
        se[t] = expf(vj);
        sf[t] = expf(ALPHA * vj);
    }
    __syncthreads();
    float th[4], A[4], Bm[4];
    #pragma unroll
    for (int r = 0; r < 4; ++r) {
        th[r] = -u[b * N + ic * 1024 + r * 256 + t];
        A[r] = 0.f; Bm[r] = 0.f;
    }
    for (int j = 0; j < SJ; j += 4) {
        float4 vv = *(const float4*)&sv[j];
        float4 ee = *(const float4*)&se[j];
        float4 ff = *(const float4*)&sf[j];
        #pragma unroll
        for (int r = 0; r < 4; ++r) {
            A[r] += (vv.x > th[r]) ? ee.x : 0.f;  Bm[r] += (vv.x > th[r]) ? 0.f : ff.x;
            A[r] += (vv.y > th[r]) ? ee.y : 0.f;  Bm[r] += (vv.y > th[r]) ? 0.f : ff.y;
            A[r] += (vv.z > th[r]) ? ee.z : 0.f;  Bm[r] += (vv.z > th[r]) ? 0.f : ff.z;
            A[r] += (vv.w > th[r]) ? ee.w : 0.f;  Bm[r] += (vv.w > th[r]) ? 0.f : ff.w;
        }
    }
    #pragma unroll
    for (int r = 0; r < 4; ++r) {
        int i = ic * 1024 + r * 256 + t;
        Ap[js * BN + b * N + i] = A[r];
        Bp[js * BN + b * N + i] = Bm[r];
    }
}

// ---------------- K4: pass-2. 512 blocks = b(8) x jc(2) x is(32).
// Reduces the 32 pass-1 partials for its 64-i slice, forms d_i, r1, r2 in LDS,
// then accumulates c_j partials for 1024 j's (IR=4).
__global__ __launch_bounds__(256) void k4_pass2(const float* __restrict__ u,
                                                const float* __restrict__ v,
                                                const float* __restrict__ Ap,
                                                const float* __restrict__ Bp,
                                                float* __restrict__ cp) {
    __shared__ float spA[256], spB[256];
    __shared__ float su[64], sr1[64], sr2[64];
    int bid = blockIdx.x;
    int b = bid >> 6, jc = (bid >> 5) & 1, is = bid & 31;
    int t = threadIdx.x;
    {   // reduce 32 partials (4 chunks of 8 across waves)
        int lane = t & 63, ch = t >> 6;
        int ii0 = b * N + is * 64 + lane;
        float pA = 0.f, pB = 0.f;
        #pragma unroll
        for (int s2 = 0; s2 < 8; ++s2) {
            int s = ch * 8 + s2;
            pA += Ap[s * BN + ii0];
            pB += Bp[s * BN + ii0];
        }
        spA[ch * 64 + lane] = pA;
        spB[ch * 64 + lane] = pB;
    }
    __syncthreads();
    if (t < 64) {
        float As = (spA[t] + spA[64 + t]) + (spA[128 + t] + spA[192 + t]);
        float Bs = (spB[t] + spB[64 + t]) + (spB[128 + t] + spB[192 + t]);
        float ui = u[b * N + is * 64 + t];
        float eu = expf(ui);
        float fu = expf(ALPHA * ui);
        float inv = 1.0f / (eu * As + fu * Bs);
        su[t] = ui; sr1[t] = eu * inv; sr2[t] = fu * inv;
    }
    __syncthreads();
    float vj[4], th[4], Cn[4], Dn[4];
    #pragma unroll
    for (int r = 0; r < 4; ++r) {
        vj[r] = v[b * N + jc * 1024 + r * 256 + t];
        th[r] = -vj[r];
        Cn[r] = 0.f; Dn[r] = 0.f;
    }
    for (int i = 0; i < 64; i += 4) {
        float4 uu = *(const float4*)&su[i];
        float4 r1 = *(const float4*)&sr1[i];
        float4 r2 = *(const float4*)&sr2[i];
        #pragma unroll
        for (int r = 0; r < 4; ++r) {
            Cn[r] += (uu.x > th[r]) ? r1.x : 0.f;  Dn[r] += (uu.x > th[r]) ? 0.f : r2.x;
            Cn[r] += (uu.y > th[r]) ? r1.y : 0.f;  Dn[r] += (uu.y > th[r]) ? 0.f : r2.y;
            Cn[r] += (uu.z > th[r]) ? r1.z : 0.f;  Dn[r] += (uu.z > th[r]) ? 0.f : r2.z;
            Cn[r] += (uu.w > th[r]) ? r1.w : 0.f;  Dn[r] += (uu.w > th[r]) ? 0.f : r2.w;
        }
    }
    #pragma unroll
    for (int r = 0; r < 4; ++r) {
        int j = jc * 1024 + r * 256 + t;
        cp[is * BN + b * N + j] = expf(vj[r]) * Cn[r] + expf(ALPHA * vj[r]) * Dn[r];
    }
}

// ---------------- K5: fused epilogue. 512 blocks = b(8) x ns(64), 256 thr.
// c_n = Sum_s cp[s][n] for 32 nodes; g[128] = Sum_n c_n h[n,:];
// out[b,f] += (1/N) * Sum_k g[k] W[k,f]  (atomicAdd, out zeroed by K2).
__global__ __launch_bounds__(256) void k5_out(const float* __restrict__ h,
                                              const float* __restrict__ W,
                                              const float* __restrict__ cp,
                                              float* __restrict__ out) {
    __shared__ float scp[256];   // 8 chunks x 32 nodes
    __shared__ float sc[32];
    __shared__ float sg2[256];   // 2 x 128
    __shared__ float sg[128];
    __shared__ float so[256];    // 4 x 64
    int b = blockIdx.x >> 6, ns = blockIdx.x & 63;
    int t = threadIdx.x;
    {   // reduce 32 cp partials for 32 nodes (8 chunks of 4)
        int n = t & 31, ch = t >> 5;
        int nn = b * N + ns * 32 + n;
        float c = 0.f;
        #pragma unroll
        for (int s2 = 0; s2 < 4; ++s2) c += cp[(ch * 4 + s2) * BN + nn];
        scp[ch * 32 + n] = c;
    }
    __syncthreads();
    if (t < 32) {
        float c = 0.f;
        #pragma unroll
        for (int ch = 0; ch < 8; ++ch) c += scp[ch * 32 + t];
        sc[t] = c;
    }
    __syncthreads();
    {   // g[k] = sum over 32 nodes of c_n * h[n,k], split across two halves
        int k = t & 127, half = t >> 7;
        float a0 = 0.f, a1 = 0.f;
        int base = b * N + ns * 32 + half * 16;
        #pragma unroll
        for (int n = 0; n < 16; n += 2) {
            a0 += sc[half * 16 + n]     * h[(size_t)(base + n)     * FIN + k];
            a1 += sc[half * 16 + n + 1] * h[(size_t)(base + n + 1) * FIN + k];
        }
        sg2[half * 128 + k] = a0 + a1;
    }
    __syncthreads();
    if (t < 128) sg[t] = sg2[t] + sg2[128 + t];
    __syncthreads();
    {   // out_part[f] = sum_k sg[k] * W[k,f], k split in 4 quarters
        int f = t & 63, q = t >> 6;
        float acc = 0.f;
        #pragma unroll
        for (int kk2 = 0; kk2 < 32; ++kk2) {
            int kk = q * 32 + kk2;
            acc += sg[kk] * W[kk * FOUT + f];
        }
        so[q * 64 + f] = acc;
    }
    __syncthreads();
    if (t < 64) {
        float r = ((so[t] + so[64 + t]) + (so[128 + t] + so[192 + t])) * (1.0f / (float)N);
        atomicAdd(out + b * FOUT + t, r);
    }
}

extern "C" void kernel_launch(void* const* d_in, const int* in_sizes, int n_in,
                              void* d_out, int out_size, void* d_ws, size_t ws_size,
                              hipStream_t stream) {
    const float* h = (const float*)d_in[0];  // [B,N,FIN]
    const float* W = (const float*)d_in[1];  // [FIN,FOUT]
    const float* a = (const float*)d_in[2];  // [2*FOUT]
    float* out = (float*)d_out;              // [B,FOUT]

    float* ws = (float*)d_ws;
    float* u  = ws;               // BN
    float* v  = u + BN;           // BN
    float* Ap = v + BN;           // JS*BN
    float* Bp = Ap + JS * BN;     // JS*BN
    float* cp = Bp + JS * BN;     // JS*BN

    k2_uv<<<512, 256, 0, stream>>>(h, W, a, u, v, out);
    k3_pass1<<<512, 256, 0, stream>>>(u, v, Ap, Bp);
    k4_pass2<<<512, 256, 0, stream>>>(u, v, Ap, Bp, cp);
    k5_out<<<512, 256, 0, stream>>>(h, W, cp, out);
}

// Round 8
// 84.901 us; speedup vs baseline: 5.1061x; 1.0224x over previous
//
#include <hip/hip_runtime.h>
#include <hip/hip_bf16.h>

// GAT layer, algebraically collapsed (validated math, absmax 0.0 in R2-R7):
//   u[b,n] = h . (W a1), v[b,n] = h . (W a2)
//   d_i = e^{u_i}*Sum_{v_j>-u_i} e^{v_j} + e^{.2u_i}*Sum_{<=} e^{.2v_j}
//   c_j = e^{v_j}*Sum_{u_i>-v_j} e^{u_i}/d_i + e^{.2v_j}*Sum_{<=} e^{.2u_i}/d_i
//   out[b,:] = (1/N) * (Sum_j c_j h[b,j,:]) @ W
// R7 lesson: dispatch-count is ~free; only kernel bodies matter. This round:
// K2 projection 64->2 shfl/thread + float4 2-nodes-per-load main loop;
// K3/K4 at SJ=32/IR=8 (ds_read_b128 amortized over 32 pairs, was 16).

#define B 8
#define N 2048
#define BN (B * N)
#define FIN 128
#define FOUT 64
#define ALPHA 0.2f
#define JS 64           // partial slices (32 elems each)
#define SJ (N / JS)     // 32 staged elements per pass block

__device__ __forceinline__ float dot4(float4 x, float4 y) {
    return x.x * y.x + x.y * y.y + x.z * y.z + x.w * y.w;
}

// ---------------- K2: u,v per node. 512 blocks x 256 thr, 32 nodes/block.
// Projection: thread (k=t>>1, half=t&1) covers 32 f's -> 2 shfl to combine.
// Main loop: one float4 load covers 2 nodes per wave; 5-level half-wave reduce.
// Block 0 zero-inits out[] for K5's atomics.
__global__ __launch_bounds__(256) void k2_uv(const float* __restrict__ h,
                                             const float* __restrict__ W,
                                             const float* __restrict__ a,
                                             float* __restrict__ u, float* __restrict__ v,
                                             float* __restrict__ out) {
    __shared__ float sa[2 * FOUT];
    __shared__ float sw[2 * FIN];
    int t = threadIdx.x, bid = blockIdx.x;
    if (bid == 0) {   // zero the 512-float output for K5's atomicAdds
        out[t] = 0.f;
        out[t + 256] = 0.f;
    }
    if (t < 2 * FOUT) sa[t] = a[t];
    __syncthreads();
    {   // w1[k] = W[k,:].a1, w2[k] = W[k,:].a2 ; k = t>>1, half covers 32 f's
        int k = t >> 1, half = t & 1;
        float p1 = 0.f, p2 = 0.f;
        #pragma unroll
        for (int i = 0; i < 8; ++i) {
            float4 w4 = *(const float4*)(W + k * FOUT + half * 32 + i * 4);
            float4 a1 = *(const float4*)(sa + half * 32 + i * 4);
            float4 a2 = *(const float4*)(sa + FOUT + half * 32 + i * 4);
            p1 += dot4(w4, a1);
            p2 += dot4(w4, a2);
        }
        p1 += __shfl_xor(p1, 1);
        p2 += __shfl_xor(p2, 1);
        if (half == 0) { sw[k] = p1; sw[FIN + k] = p2; }
    }
    __syncthreads();
    int wave = t >> 6, lane = t & 63;
    int hl = lane & 31;              // lane within half-wave
    const float4 w1x = *(const float4*)(sw + hl * 4);
    const float4 w2x = *(const float4*)(sw + FIN + hl * 4);
    int node0 = bid * 32 + wave * 8;
    #pragma unroll
    for (int it = 0; it < 4; ++it) {
        int node = node0 + it * 2 + (lane >> 5);   // 2 nodes per wave-iter
        const float4 hx = *(const float4*)(h + (size_t)node * FIN + hl * 4);
        float p1 = dot4(hx, w1x);
        float p2 = dot4(hx, w2x);
        #pragma unroll
        for (int o = 1; o < 32; o <<= 1) {
            p1 += __shfl_xor(p1, o);
            p2 += __shfl_xor(p2, o);
        }
        if (hl == 0) { u[node] = p1; v[node] = p2; }
    }
}

// ---------------- K3: pass-1 partials. 512 blocks = b(8) x js(64).
// IR=8 rows/thread (covers all 2048 i); SJ=32 j's staged in LDS.
__global__ __launch_bounds__(256) void k3_pass1(const float* __restrict__ u,
                                                const float* __restrict__ v,
                                                float* __restrict__ Ap, float* __restrict__ Bp) {
    __shared__ float sv[SJ], se[SJ], sf[SJ];
    int bid = blockIdx.x;
    int b = bid >> 6, js = bid & 63;
    int t = threadIdx.x;
    if (t < SJ) {
        float vj = v[b * N + js * SJ + t];
        sv[t] = vj;
        se[t] = expf(vj);
        sf[t] = expf(ALPHA * vj);
    }
    __syncthreads();
    float th[8], A[8], Bm[8];
    #pragma unroll
    for (int r = 0; r < 8; ++r) {
        th[r] = -u[b * N + r * 256 + t];
        A[r] = 0.f; Bm[r] = 0.f;
    }
    #pragma unroll
    for (int j = 0; j < SJ; j += 4) {
        float4 vv = *(const float4*)&sv[j];
        float4 ee = *(const float4*)&se[j];
        float4 ff = *(const float4*)&sf[j];
        #pragma unroll
        for (int r = 0; r < 8; ++r) {
            A[r] += (vv.x > th[r]) ? ee.x : 0.f;  Bm[r] += (vv.x > th[r]) ? 0.f : ff.x;
            A[r] += (vv.y > th[r]) ? ee.y : 0.f;  Bm[r] += (vv.y > th[r]) ? 0.f : ff.y;
            A[r] += (vv.z > th[r]) ? ee.z : 0.f;  Bm[r] += (vv.z > th[r]) ? 0.f : ff.z;
            A[r] += (vv.w > th[r]) ? ee.w : 0.f;  Bm[r] += (vv.w > th[r]) ? 0.f : ff.w;
        }
    }
    #pragma unroll
    for (int r = 0; r < 8; ++r) {
        int i = r * 256 + t;
        Ap[js * BN + b * N + i] = A[r];
        Bp[js * BN + b * N + i] = Bm[r];
    }
}

// ---------------- K4: pass-2. 512 blocks = b(8) x is(64).
// Reduces 64 pass-1 partials for its 32-i slice, forms d_i, r1, r2 in LDS,
// then accumulates c_j partials for all 2048 j's (8 rows/thread).
__global__ __launch_bounds__(256) void k4_pass2(const float* __restrict__ u,
                                                const float* __restrict__ v,
                                                const float* __restrict__ Ap,
                                                const float* __restrict__ Bp,
                                                float* __restrict__ cp) {
    __shared__ float spA[256], spB[256];
    __shared__ float su[SJ], sr1[SJ], sr2[SJ];
    int bid = blockIdx.x;
    int b = bid >> 6, is = bid & 63;
    int t = threadIdx.x;
    {   // reduce 64 partials for 32 i's (8 chunks of 8 across threads)
        int n = t & 31, ch = t >> 5;
        int ii0 = b * N + is * 32 + n;
        float pA = 0.f, pB = 0.f;
        #pragma unroll
        for (int s2 = 0; s2 < 8; ++s2) {
            int s = ch * 8 + s2;
            pA += Ap[s * BN + ii0];
            pB += Bp[s * BN + ii0];
        }
        spA[ch * 32 + n] = pA;
        spB[ch * 32 + n] = pB;
    }
    __syncthreads();
    if (t < 32) {
        float As = 0.f, Bs = 0.f;
        #pragma unroll
        for (int ch = 0; ch < 8; ++ch) {
            As += spA[ch * 32 + t];
            Bs += spB[ch * 32 + t];
        }
        float ui = u[b * N + is * 32 + t];
        float eu = expf(ui);
        float fu = expf(ALPHA * ui);
        float inv = 1.0f / (eu * As + fu * Bs);
        su[t] = ui; sr1[t] = eu * inv; sr2[t] = fu * inv;
    }
    __syncthreads();
    float vj[8], th[8], Cn[8], Dn[8];
    #pragma unroll
    for (int r = 0; r < 8; ++r) {
        vj[r] = v[b * N + r * 256 + t];
        th[r] = -vj[r];
        Cn[r] = 0.f; Dn[r] = 0.f;
    }
    #pragma unroll
    for (int i = 0; i < SJ; i += 4) {
        float4 uu = *(const float4*)&su[i];
        float4 r1 = *(const float4*)&sr1[i];
        float4 r2 = *(const float4*)&sr2[i];
        #pragma unroll
        for (int r = 0; r < 8; ++r) {
            Cn[r] += (uu.x > th[r]) ? r1.x : 0.f;  Dn[r] += (uu.x > th[r]) ? 0.f : r2.x;
            Cn[r] += (uu.y > th[r]) ? r1.y : 0.f;  Dn[r] += (uu.y > th[r]) ? 0.f : r2.y;
            Cn[r] += (uu.z > th[r]) ? r1.z : 0.f;  Dn[r] += (uu.z > th[r]) ? 0.f : r2.z;
            Cn[r] += (uu.w > th[r]) ? r1.w : 0.f;  Dn[r] += (uu.w > th[r]) ? 0.f : r2.w;
        }
    }
    #pragma unroll
    for (int r = 0; r < 8; ++r) {
        int j = r * 256 + t;
        cp[is * BN + b * N + j] = expf(vj[r]) * Cn[r] + expf(ALPHA * vj[r]) * Dn[r];
    }
}

// ---------------- K5: fused epilogue. 512 blocks = b(8) x ns(64), 256 thr.
// c_n = Sum_s cp[s][n] (64 partials) for 32 nodes; g[128] = Sum_n c_n h[n,:];
// out[b,f] += (1/N) * Sum_k g[k] W[k,f]  (atomicAdd, out zeroed by K2).
__global__ __launch_bounds__(256) void k5_out(const float* __restrict__ h,
                                              const float* __restrict__ W,
                                              const float* __restrict__ cp,
                                              float* __restrict__ out) {
    __shared__ float scp[256];   // 8 chunks x 32 nodes
    __shared__ float sc[32];
    __shared__ float sg2[256];   // 2 x 128
    __shared__ float sg[128];
    __shared__ float so[256];    // 4 x 64
    int b = blockIdx.x >> 6, ns = blockIdx.x & 63;
    int t = threadIdx.x;
    {   // reduce 64 cp partials for 32 nodes (8 chunks of 8)
        int n = t & 31, ch = t >> 5;
        int nn = b * N + ns * 32 + n;
        float c = 0.f;
        #pragma unroll
        for (int s2 = 0; s2 < 8; ++s2) c += cp[(ch * 8 + s2) * BN + nn];
        scp[ch * 32 + n] = c;
    }
    __syncthreads();
    if (t < 32) {
        float c = 0.f;
        #pragma unroll
        for (int ch = 0; ch < 8; ++ch) c += scp[ch * 32 + t];
        sc[t] = c;
    }
    __syncthreads();
    {   // g[k] = sum over 32 nodes of c_n * h[n,k], split across two halves
        int k = t & 127, half = t >> 7;
        float a0 = 0.f, a1 = 0.f;
        int base = b * N + ns * 32 + half * 16;
        #pragma unroll
        for (int n = 0; n < 16; n += 2) {
            a0 += sc[half * 16 + n]     * h[(size_t)(base + n)     * FIN + k];
            a1 += sc[half * 16 + n + 1] * h[(size_t)(base + n + 1) * FIN + k];
        }
        sg2[half * 128 + k] = a0 + a1;
    }
    __syncthreads();
    if (t < 128) sg[t] = sg2[t] + sg2[128 + t];
    __syncthreads();
    {   // out_part[f] = sum_k sg[k] * W[k,f], k split in 4 quarters
        int f = t & 63, q = t >> 6;
        float acc = 0.f;
        #pragma unroll
        for (int kk2 = 0; kk2 < 32; ++kk2) {
            int kk = q * 32 + kk2;
            acc += sg[kk] * W[kk * FOUT + f];
        }
        so[q * 64 + f] = acc;
    }
    __syncthreads();
    if (t < 64) {
        float r = ((so[t] + so[64 + t]) + (so[128 + t] + so[192 + t])) * (1.0f / (float)N);
        atomicAdd(out + b * FOUT + t, r);
    }
}

extern "C" void kernel_launch(void* const* d_in, const int* in_sizes, int n_in,
                              void* d_out, int out_size, void* d_ws, size_t ws_size,
                              hipStream_t stream) {
    const float* h = (const float*)d_in[0];  // [B,N,FIN]
    const float* W = (const float*)d_in[1];  // [FIN,FOUT]
    const float* a = (const float*)d_in[2];  // [2*FOUT]
    float* out = (float*)d_out;              // [B,FOUT]

    float* ws = (float*)d_ws;
    float* u  = ws;               // BN
    float* v  = u + BN;           // BN
    float* Ap = v + BN;           // JS*BN
    float* Bp = Ap + JS * BN;     // JS*BN
    float* cp = Bp + JS * BN;     // JS*BN

    k2_uv<<<512, 256, 0, stream>>>(h, W, a, u, v, out);
    k3_pass1<<<512, 256, 0, stream>>>(u, v, Ap, Bp);
    k4_pass2<<<512, 256, 0, stream>>>(u, v, Ap, Bp, cp);
    k5_out<<<512, 256, 0, stream>>>(h, W, cp, out);
}